// Round 7
// baseline (293.304 us; speedup 1.0000x reference)
//
#include <hip/hip_runtime.h>
#include <hip/hip_bf16.h>
#include <math.h>

#define SEQ 4096
#define EDIM 768
#define NHEAD 12
#define HDIM 64
#define SE (SEQ * EDIM)
#define WMAT (EDIM * EDIM)
#define QSCALE 0.180336880111f  // 0.125 * log2(e)

typedef __attribute__((ext_vector_type(8))) __bf16 bf16x8;
typedef __attribute__((ext_vector_type(4))) float f32x4;
typedef __attribute__((ext_vector_type(8))) unsigned short u16x8;
typedef unsigned short ushort_t;
typedef unsigned int uint_t;

#define MFMA16(a, b, c) __builtin_amdgcn_mfma_f32_16x16x32_bf16(a, b, c, 0, 0, 0)
#define GLOAD_LDS16(g, l)                                          \
  __builtin_amdgcn_global_load_lds(                                \
      (const __attribute__((address_space(1))) void*)(g),          \
      (__attribute__((address_space(3))) void*)(l), 16, 0, 0)

__device__ __forceinline__ unsigned short bfbits(float x) {
  return __builtin_bit_cast(unsigned short, (__bf16)x);
}
__device__ __forceinline__ void split1(float x, unsigned short* h,
                                       unsigned short* l) {
  __bf16 hb = (__bf16)x;
  *h = __builtin_bit_cast(unsigned short, hb);
  *l = __builtin_bit_cast(unsigned short, (__bf16)(x - (float)hb));
}
__device__ __forceinline__ bf16x8 ones8() {
  u16x8 u;
#pragma unroll
  for (int e = 0; e < 8; ++e) u[e] = 0x3F80;  // bf16 1.0
  return __builtin_bit_cast(bf16x8, u);
}

// ---------------------------------------------------------------------------
// Prep: round Wq/Wk/Wv to bf16; split Wo hi/lo; round x to bf16.
// ---------------------------------------------------------------------------
__global__ __launch_bounds__(256) void wprep_kernel(
    const float* __restrict__ W0, const float* __restrict__ W1,
    const float* __restrict__ W2, const float* __restrict__ W3,
    ushort_t* __restrict__ WB, ushort_t* __restrict__ WOH,
    ushort_t* __restrict__ WOL) {
  const int m = blockIdx.y;
  const float* src = (m == 0) ? W0 : (m == 1) ? W1 : (m == 2) ? W2 : W3;
  const size_t i = ((size_t)blockIdx.x * 256 + threadIdx.x) * 8;
  float4 a = *(const float4*)(src + i);
  float4 b = *(const float4*)(src + i + 4);
  float fv[8] = {a.x, a.y, a.z, a.w, b.x, b.y, b.z, b.w};
  if (m < 3) {
    u16x8 hh;
#pragma unroll
    for (int e = 0; e < 8; ++e) hh[e] = bfbits(fv[e]);
    *(u16x8*)(WB + (size_t)m * WMAT + i) = hh;
  } else {
    u16x8 hh, ll;
#pragma unroll
    for (int e = 0; e < 8; ++e) {
      unsigned short x, y;
      split1(fv[e], &x, &y);
      hh[e] = x;
      ll[e] = y;
    }
    *(u16x8*)(WOH + i) = hh;
    *(u16x8*)(WOL + i) = ll;
  }
}

__global__ __launch_bounds__(256) void xprep_kernel(
    const float* __restrict__ x, ushort_t* __restrict__ xb) {
  const size_t i = ((size_t)blockIdx.x * 256 + threadIdx.x) * 8;
  float4 a = *(const float4*)(x + i);
  float4 b = *(const float4*)(x + i + 4);
  float fv[8] = {a.x, a.y, a.z, a.w, b.x, b.y, b.z, b.w};
  u16x8 hh;
#pragma unroll
  for (int e = 0; e < 8; ++e) hh[e] = bfbits(fv[e]);
  *(u16x8*)(xb + i) = hh;
}

// ---------------------------------------------------------------------------
// Single-bf16 MFMA GEMM (for QKV): out_bf16 = bf16((A@B^T + bias) * scale).
// ---------------------------------------------------------------------------
__global__ __launch_bounds__(256) void qkv_kernel(
    const ushort_t* __restrict__ XB, const ushort_t* __restrict__ WB,
    const float* __restrict__ bq, const float* __restrict__ bk,
    const float* __restrict__ bv, ushort_t* __restrict__ QB,
    ushort_t* __restrict__ KB, ushort_t* __restrict__ VB) {
  __shared__ __align__(16) ushort_t AS[128][32];
  __shared__ __align__(16) ushort_t BS[128][32];

  const int z = blockIdx.z;
  const ushort_t* Bmat = WB + (size_t)z * WMAT;
  const float* bias = (z == 0) ? bq : (z == 1) ? bk : bv;
  ushort_t* outp = (z == 0) ? QB : (z == 1) ? KB : VB;
  const float scale = (z == 0) ? QSCALE : 1.0f;

  const int t = threadIdx.x;
  const int lane = t & 63;
  const int w = t >> 6;
  const int tn = t & 15;
  const int g = (t >> 4) & 3;
  const int wr = w >> 1, wc = w & 1;
  const int m0 = blockIdx.x * 128;
  const int n0 = blockIdx.y * 128;

  f32x4 acc[4][4];
#pragma unroll
  for (int mi = 0; mi < 4; ++mi)
#pragma unroll
    for (int nj = 0; nj < 4; ++nj) acc[mi][nj] = (f32x4){0.f, 0.f, 0.f, 0.f};

  const int crow = lane >> 2;
  const int ccol = (lane & 3) * 8;

  for (int k0 = 0; k0 < EDIM; k0 += 32) {
    __syncthreads();
#pragma unroll
    for (int i = 0; i < 2; ++i) {
      const int ch = w + 4 * i;
      const int row = ch * 16 + crow;
      GLOAD_LDS16(XB + (size_t)(m0 + row) * EDIM + k0 + ccol, &AS[ch * 16][0]);
      GLOAD_LDS16(Bmat + (size_t)(n0 + row) * EDIM + k0 + ccol, &BS[ch * 16][0]);
    }
    __syncthreads();

    bf16x8 ah[4], bh[4];
#pragma unroll
    for (int mi = 0; mi < 4; ++mi)
      ah[mi] = __builtin_bit_cast(
          bf16x8, *(const u16x8*)&AS[wr * 64 + mi * 16 + tn][8 * g]);
#pragma unroll
    for (int nj = 0; nj < 4; ++nj)
      bh[nj] = __builtin_bit_cast(
          bf16x8, *(const u16x8*)&BS[wc * 64 + nj * 16 + tn][8 * g]);
#pragma unroll
    for (int mi = 0; mi < 4; ++mi)
#pragma unroll
      for (int nj = 0; nj < 4; ++nj)
        acc[mi][nj] = MFMA16(ah[mi], bh[nj], acc[mi][nj]);
  }

#pragma unroll
  for (int mi = 0; mi < 4; ++mi) {
    const int rb = m0 + wr * 64 + mi * 16 + 4 * g;
#pragma unroll
    for (int nj = 0; nj < 4; ++nj) {
      const int col = n0 + wc * 64 + nj * 16 + tn;
      const float bb = bias[col];
#pragma unroll
      for (int r = 0; r < 4; ++r)
        outp[(size_t)(rb + r) * EDIM + col] =
            bfbits((acc[mi][nj][r] + bb) * scale);
    }
  }
}

// ---------------------------------------------------------------------------
// 3-term split MFMA GEMM (for proj): fp32-accurate, fp32 out + bias.
// ---------------------------------------------------------------------------
__global__ __launch_bounds__(256) void proj_kernel(
    const ushort_t* __restrict__ Ah, const ushort_t* __restrict__ Al,
    const ushort_t* __restrict__ Bh, const ushort_t* __restrict__ Bl,
    const float* __restrict__ bias, float* __restrict__ outf) {
  __shared__ __align__(16) ushort_t AhS[128][32];
  __shared__ __align__(16) ushort_t AlS[128][32];
  __shared__ __align__(16) ushort_t BhS[128][32];
  __shared__ __align__(16) ushort_t BlS[128][32];

  const int t = threadIdx.x;
  const int lane = t & 63;
  const int w = t >> 6;
  const int tn = t & 15;
  const int g = (t >> 4) & 3;
  const int wr = w >> 1, wc = w & 1;
  const int m0 = blockIdx.x * 128;
  const int n0 = blockIdx.y * 128;

  f32x4 acc[4][4];
#pragma unroll
  for (int mi = 0; mi < 4; ++mi)
#pragma unroll
    for (int nj = 0; nj < 4; ++nj) acc[mi][nj] = (f32x4){0.f, 0.f, 0.f, 0.f};

  const int crow = lane >> 2;
  const int ccol = (lane & 3) * 8;

  for (int k0 = 0; k0 < EDIM; k0 += 32) {
    __syncthreads();
#pragma unroll
    for (int i = 0; i < 2; ++i) {
      const int ch = w + 4 * i;
      const int row = ch * 16 + crow;
      const size_t ga = (size_t)(m0 + row) * EDIM + k0 + ccol;
      const size_t gb = (size_t)(n0 + row) * EDIM + k0 + ccol;
      GLOAD_LDS16(Ah + ga, &AhS[ch * 16][0]);
      GLOAD_LDS16(Al + ga, &AlS[ch * 16][0]);
      GLOAD_LDS16(Bh + gb, &BhS[ch * 16][0]);
      GLOAD_LDS16(Bl + gb, &BlS[ch * 16][0]);
    }
    __syncthreads();

    bf16x8 ah[4], al[4], bh[4], bl[4];
#pragma unroll
    for (int mi = 0; mi < 4; ++mi) {
      ah[mi] = __builtin_bit_cast(
          bf16x8, *(const u16x8*)&AhS[wr * 64 + mi * 16 + tn][8 * g]);
      al[mi] = __builtin_bit_cast(
          bf16x8, *(const u16x8*)&AlS[wr * 64 + mi * 16 + tn][8 * g]);
    }
#pragma unroll
    for (int nj = 0; nj < 4; ++nj) {
      bh[nj] = __builtin_bit_cast(
          bf16x8, *(const u16x8*)&BhS[wc * 64 + nj * 16 + tn][8 * g]);
      bl[nj] = __builtin_bit_cast(
          bf16x8, *(const u16x8*)&BlS[wc * 64 + nj * 16 + tn][8 * g]);
    }
#pragma unroll
    for (int mi = 0; mi < 4; ++mi)
#pragma unroll
      for (int nj = 0; nj < 4; ++nj)
        acc[mi][nj] = MFMA16(ah[mi], bh[nj], acc[mi][nj]);
#pragma unroll
    for (int mi = 0; mi < 4; ++mi)
#pragma unroll
      for (int nj = 0; nj < 4; ++nj)
        acc[mi][nj] = MFMA16(al[mi], bh[nj], acc[mi][nj]);
#pragma unroll
    for (int mi = 0; mi < 4; ++mi)
#pragma unroll
      for (int nj = 0; nj < 4; ++nj)
        acc[mi][nj] = MFMA16(ah[mi], bl[nj], acc[mi][nj]);
  }

#pragma unroll
  for (int mi = 0; mi < 4; ++mi) {
    const int rb = m0 + wr * 64 + mi * 16 + 4 * g;
#pragma unroll
    for (int nj = 0; nj < 4; ++nj) {
      const int col = n0 + wc * 64 + nj * 16 + tn;
      const float bb = bias[col];
#pragma unroll
      for (int r = 0; r < 4; ++r)
        outf[(size_t)(rb + r) * EDIM + col] = acc[mi][nj][r] + bb;
    }
  }
}

// ---------------------------------------------------------------------------
// MFMA flash attention, round-5 shape (256 thr, 4 waves x 16 q-rows, 12
// waves/CU) with the round-6 traffic lesson applied occupancy-neutrally:
//  - K fragments load DIRECTLY from global (L1/L2-served; A-frag layout
//    row=lane&15, k=(lane>>4)*8+e) -> no K staging, no K LDS reads.
//  - Swapped QK^T: s = mfma(K, Q) -> lane holds P[q=tn][key=16kb+4g+r];
//    P written as packed b64 (4 instrs) instead of 16 scalar b16 stores.
//  - V staged transposed in LDS (T14 reg preload), PV + ones-MFMA rowsum,
//    no-max exp2 softmax. C written hi/lo split for the proj 3-term GEMM.
// ---------------------------------------------------------------------------
__global__ __launch_bounds__(256) void attn_kernel(
    const ushort_t* __restrict__ QB, const ushort_t* __restrict__ KBg,
    const ushort_t* __restrict__ Vg, ushort_t* __restrict__ Ch_g,
    ushort_t* __restrict__ Cl_g) {
  constexpr int DP = HDIM + 8;  // 72
  __shared__ __align__(16) ushort_t Vt[HDIM][DP];   // Vt[d][key]
  __shared__ __align__(16) ushort_t Ps[4][16][DP];  // per-wave P[q][key]

  const int t = threadIdx.x;
  const int tn = t & 15;
  const int g = (t >> 4) & 3;
  const int kg = g * 8;
  const int wid = t >> 6;
  const int h = blockIdx.y;
  const int q0 = blockIdx.x * 64;
  const int hoff = h * HDIM;

  // Q fragments (pre-scaled bf16) — serve as MFMA B-operand after the swap
  bf16x8 qb[2];
  {
    const size_t qoff = (size_t)(q0 + 16 * wid + tn) * EDIM + hoff;
#pragma unroll
    for (int st = 0; st < 2; ++st)
      qb[st] = __builtin_bit_cast(bf16x8,
                                  *(const u16x8*)(QB + qoff + 32 * st + kg));
  }

  // V staging roles (256 threads)
  const int vkey = (t & 31) * 2;   // two keys per thread
  const int vd0 = (t >> 5) * 8;    // 8 dims

  u16x8 vv0, vv1;
  {
    const size_t vo = (size_t)vkey * EDIM + hoff + vd0;
    vv0 = *(const u16x8*)(Vg + vo);
    vv1 = *(const u16x8*)(Vg + vo + EDIM);
  }

  const bf16x8 ones = ones8();
  f32x4 o[4], lsum;
#pragma unroll
  for (int j = 0; j < 4; ++j) o[j] = (f32x4){0.f, 0.f, 0.f, 0.f};
  lsum = (f32x4){0.f, 0.f, 0.f, 0.f};

  for (int k0 = 0; k0 < SEQ; k0 += 64) {
    // issue K fragment loads for this tile (global; hide under V barriers)
    bf16x8 kc[4][2];
#pragma unroll
    for (int kb = 0; kb < 4; ++kb) {
      const ushort_t* kp = KBg + (size_t)(k0 + 16 * kb + tn) * EDIM + hoff + kg;
      kc[kb][0] = __builtin_bit_cast(bf16x8, *(const u16x8*)kp);
      kc[kb][1] = __builtin_bit_cast(bf16x8, *(const u16x8*)(kp + 32));
    }

    __syncthreads();  // previous tile's V reads complete
    // staged V regs -> LDS (transposed)
#pragma unroll
    for (int i = 0; i < 8; ++i)
      *(uint_t*)&Vt[vd0 + i][vkey] =
          (uint_t)vv0[i] | ((uint_t)vv1[i] << 16);
    if (k0 + 64 < SEQ) {  // T14 preload next V tile
      const size_t vo = (size_t)(k0 + 64 + vkey) * EDIM + hoff + vd0;
      vv0 = *(const u16x8*)(Vg + vo);
      vv1 = *(const u16x8*)(Vg + vo + EDIM);
    }
    __syncthreads();  // Vt ready

    // S^T = K Q : lane holds S[key=16kb+4g+r][q=tn]
    f32x4 s[4];
#pragma unroll
    for (int kb = 0; kb < 4; ++kb) {
      s[kb] = (f32x4){0.f, 0.f, 0.f, 0.f};
      s[kb] = MFMA16(kc[kb][0], qb[0], s[kb]);
      s[kb] = MFMA16(kc[kb][1], qb[1], s[kb]);
    }

    // p = 2^s; packed P write: row q=tn, cols 16kb+4g..+3 (one b64 per kb)
#pragma unroll
    for (int kb = 0; kb < 4; ++kb) {
      uint_t lo = (uint_t)bfbits(exp2f(s[kb][0])) |
                  ((uint_t)bfbits(exp2f(s[kb][1])) << 16);
      uint_t hi = (uint_t)bfbits(exp2f(s[kb][2])) |
                  ((uint_t)bfbits(exp2f(s[kb][3])) << 16);
      uint2 pk;
      pk.x = lo;
      pk.y = hi;
      *(uint2*)&Ps[wid][tn][16 * kb + 4 * g] = pk;
    }

    // O += P V ; lsum += P @ ones (per-wave P, wave-local sync via lgkmcnt)
    bf16x8 pa[2];
#pragma unroll
    for (int st = 0; st < 2; ++st)
      pa[st] = __builtin_bit_cast(
          bf16x8, *(const u16x8*)&Ps[wid][tn][32 * st + kg]);
#pragma unroll
    for (int j = 0; j < 4; ++j)
#pragma unroll
      for (int st = 0; st < 2; ++st) {
        const bf16x8 vb = __builtin_bit_cast(
            bf16x8, *(const u16x8*)&Vt[j * 16 + tn][32 * st + kg]);
        o[j] = MFMA16(pa[st], vb, o[j]);
      }
    lsum = MFMA16(pa[0], ones, lsum);
    lsum = MFMA16(pa[1], ones, lsum);
  }

  // epilogue: normalize, split hi/lo, store C (rows 4g+r — layout unchanged)
#pragma unroll
  for (int r = 0; r < 4; ++r) {
    const float inv = 1.f / lsum[r];
#pragma unroll
    for (int j = 0; j < 4; ++j) {
      const float val = o[j][r] * inv;
      unsigned short hh, ll;
      split1(val, &hh, &ll);
      const size_t idx =
          (size_t)(q0 + 16 * wid + 4 * g + r) * EDIM + hoff + 16 * j + tn;
      Ch_g[idx] = hh;
      Cl_g[idx] = ll;
    }
  }
}

extern "C" void kernel_launch(void* const* d_in, const int* in_sizes, int n_in,
                              void* d_out, int out_size, void* d_ws,
                              size_t ws_size, hipStream_t stream) {
  const float* x  = (const float*)d_in[0];
  const float* Wq = (const float*)d_in[1];
  const float* bq = (const float*)d_in[2];
  const float* Wk = (const float*)d_in[3];
  const float* bk = (const float*)d_in[4];
  const float* Wv = (const float*)d_in[5];
  const float* bv = (const float*)d_in[6];
  const float* Wo = (const float*)d_in[7];
  const float* bo = (const float*)d_in[8];
  float* out = (float*)d_out;

  // ws layout, u16 elements (~43.7 MB)
  ushort_t* WB  = (ushort_t*)d_ws;              // 3*WMAT (Wq,Wk,Wv bf16)
  ushort_t* WOH = WB + (size_t)3 * WMAT;        // WMAT
  ushort_t* WOL = WOH + (size_t)WMAT;           // WMAT
  ushort_t* XB  = WOL + (size_t)WMAT;           // SE
  ushort_t* QB  = XB + (size_t)SE;              // SE
  ushort_t* KB  = QB + (size_t)SE;              // SE
  ushort_t* VB  = KB + (size_t)SE;              // SE
  ushort_t* CH  = VB + (size_t)SE;              // SE
  ushort_t* CL  = CH + (size_t)SE;              // SE

  dim3 gw(WMAT / 2048, 4);
  wprep_kernel<<<gw, 256, 0, stream>>>(Wq, Wk, Wv, Wo, WB, WOH, WOL);
  xprep_kernel<<<SE / 2048, 256, 0, stream>>>(x, XB);

  dim3 gq(SEQ / 128, EDIM / 128, 3);
  qkv_kernel<<<gq, 256, 0, stream>>>(XB, WB, bq, bk, bv, QB, KB, VB);

  dim3 ga(SEQ / 64, NHEAD);
  attn_kernel<<<ga, 256, 0, stream>>>(QB, KB, VB, CH, CL);

  dim3 go(SEQ / 128, EDIM / 128);
  proj_kernel<<<go, 256, 0, stream>>>(CH, CL, WOH, WOL, bo, out);
}

// Round 8
// 186.120 us; speedup vs baseline: 1.5759x; 1.5759x over previous
//
#include <hip/hip_runtime.h>
#include <hip/hip_bf16.h>
#include <math.h>

#define SEQ 4096
#define EDIM 768
#define NHEAD 12
#define HDIM 64
#define SE (SEQ * EDIM)
#define WMAT (EDIM * EDIM)
#define QSCALE 0.180336880111f  // 0.125 * log2(e)

typedef __attribute__((ext_vector_type(8))) __bf16 bf16x8;
typedef __attribute__((ext_vector_type(4))) float f32x4;
typedef __attribute__((ext_vector_type(8))) unsigned short u16x8;
typedef unsigned short ushort_t;
typedef unsigned int uint_t;

#define MFMA16(a, b, c) __builtin_amdgcn_mfma_f32_16x16x32_bf16(a, b, c, 0, 0, 0)
#define GLOAD_LDS16(g, l)                                          \
  __builtin_amdgcn_global_load_lds(                                \
      (const __attribute__((address_space(1))) void*)(g),          \
      (__attribute__((address_space(3))) void*)(l), 16, 0, 0)

__device__ __forceinline__ unsigned short bfbits(float x) {
  return __builtin_bit_cast(unsigned short, (__bf16)x);
}
__device__ __forceinline__ void split1(float x, unsigned short* h,
                                       unsigned short* l) {
  __bf16 hb = (__bf16)x;
  *h = __builtin_bit_cast(unsigned short, hb);
  *l = __builtin_bit_cast(unsigned short, (__bf16)(x - (float)hb));
}
__device__ __forceinline__ bf16x8 ones8() {
  u16x8 u;
#pragma unroll
  for (int e = 0; e < 8; ++e) u[e] = 0x3F80;  // bf16 1.0
  return __builtin_bit_cast(bf16x8, u);
}

// ---------------------------------------------------------------------------
// Prep: round Wq/Wk/Wv to bf16; split Wo hi/lo; round x to bf16.
// ---------------------------------------------------------------------------
__global__ __launch_bounds__(256) void wprep_kernel(
    const float* __restrict__ W0, const float* __restrict__ W1,
    const float* __restrict__ W2, const float* __restrict__ W3,
    ushort_t* __restrict__ WB, ushort_t* __restrict__ WOH,
    ushort_t* __restrict__ WOL) {
  const int m = blockIdx.y;
  const float* src = (m == 0) ? W0 : (m == 1) ? W1 : (m == 2) ? W2 : W3;
  const size_t i = ((size_t)blockIdx.x * 256 + threadIdx.x) * 8;
  float4 a = *(const float4*)(src + i);
  float4 b = *(const float4*)(src + i + 4);
  float fv[8] = {a.x, a.y, a.z, a.w, b.x, b.y, b.z, b.w};
  if (m < 3) {
    u16x8 hh;
#pragma unroll
    for (int e = 0; e < 8; ++e) hh[e] = bfbits(fv[e]);
    *(u16x8*)(WB + (size_t)m * WMAT + i) = hh;
  } else {
    u16x8 hh, ll;
#pragma unroll
    for (int e = 0; e < 8; ++e) {
      unsigned short x, y;
      split1(fv[e], &x, &y);
      hh[e] = x;
      ll[e] = y;
    }
    *(u16x8*)(WOH + i) = hh;
    *(u16x8*)(WOL + i) = ll;
  }
}

__global__ __launch_bounds__(256) void xprep_kernel(
    const float* __restrict__ x, ushort_t* __restrict__ xb) {
  const size_t i = ((size_t)blockIdx.x * 256 + threadIdx.x) * 8;
  float4 a = *(const float4*)(x + i);
  float4 b = *(const float4*)(x + i + 4);
  float fv[8] = {a.x, a.y, a.z, a.w, b.x, b.y, b.z, b.w};
  u16x8 hh;
#pragma unroll
  for (int e = 0; e < 8; ++e) hh[e] = bfbits(fv[e]);
  *(u16x8*)(xb + i) = hh;
}

// ---------------------------------------------------------------------------
// V transpose: VB [4096][768] -> VT [768][4096], per-head 64x64 tiles.
// Odd LDS stride (65) -> ~2-way banks on both the write and gather sides.
// ---------------------------------------------------------------------------
__global__ __launch_bounds__(256) void vtrans_kernel(
    const ushort_t* __restrict__ VB, ushort_t* __restrict__ VT) {
  __shared__ ushort_t T[64][65];
  const int t = threadIdx.x;
  const int s0 = blockIdx.x * 64;
  const int hoff = blockIdx.y * 64;
  const int r = t >> 2, c = (t & 3) * 16;
  u16x8 a = *(const u16x8*)(VB + (size_t)(s0 + r) * EDIM + hoff + c);
  u16x8 b = *(const u16x8*)(VB + (size_t)(s0 + r) * EDIM + hoff + c + 8);
#pragma unroll
  for (int e = 0; e < 8; ++e) {
    T[r][c + e] = a[e];
    T[r][c + 8 + e] = b[e];
  }
  __syncthreads();
  u16x8 w0, w1;
#pragma unroll
  for (int e = 0; e < 8; ++e) {
    w0[e] = T[c + e][r];
    w1[e] = T[c + 8 + e][r];
  }
  *(u16x8*)(VT + (size_t)(hoff + r) * SEQ + s0 + c) = w0;
  *(u16x8*)(VT + (size_t)(hoff + r) * SEQ + s0 + c + 8) = w1;
}

// ---------------------------------------------------------------------------
// Single-bf16 MFMA GEMM (for QKV): out_bf16 = bf16((A@B^T + bias) * scale).
// ---------------------------------------------------------------------------
__global__ __launch_bounds__(256) void qkv_kernel(
    const ushort_t* __restrict__ XB, const ushort_t* __restrict__ WB,
    const float* __restrict__ bq, const float* __restrict__ bk,
    const float* __restrict__ bv, ushort_t* __restrict__ QB,
    ushort_t* __restrict__ KB, ushort_t* __restrict__ VB) {
  __shared__ __align__(16) ushort_t AS[128][32];
  __shared__ __align__(16) ushort_t BS[128][32];

  const int z = blockIdx.z;
  const ushort_t* Bmat = WB + (size_t)z * WMAT;
  const float* bias = (z == 0) ? bq : (z == 1) ? bk : bv;
  ushort_t* outp = (z == 0) ? QB : (z == 1) ? KB : VB;
  const float scale = (z == 0) ? QSCALE : 1.0f;

  const int t = threadIdx.x;
  const int lane = t & 63;
  const int w = t >> 6;
  const int tn = t & 15;
  const int g = (t >> 4) & 3;
  const int wr = w >> 1, wc = w & 1;
  const int m0 = blockIdx.x * 128;
  const int n0 = blockIdx.y * 128;

  f32x4 acc[4][4];
#pragma unroll
  for (int mi = 0; mi < 4; ++mi)
#pragma unroll
    for (int nj = 0; nj < 4; ++nj) acc[mi][nj] = (f32x4){0.f, 0.f, 0.f, 0.f};

  const int crow = lane >> 2;
  const int ccol = (lane & 3) * 8;

  for (int k0 = 0; k0 < EDIM; k0 += 32) {
    __syncthreads();
#pragma unroll
    for (int i = 0; i < 2; ++i) {
      const int ch = w + 4 * i;
      const int row = ch * 16 + crow;
      GLOAD_LDS16(XB + (size_t)(m0 + row) * EDIM + k0 + ccol, &AS[ch * 16][0]);
      GLOAD_LDS16(Bmat + (size_t)(n0 + row) * EDIM + k0 + ccol, &BS[ch * 16][0]);
    }
    __syncthreads();

    bf16x8 ah[4], bh[4];
#pragma unroll
    for (int mi = 0; mi < 4; ++mi)
      ah[mi] = __builtin_bit_cast(
          bf16x8, *(const u16x8*)&AS[wr * 64 + mi * 16 + tn][8 * g]);
#pragma unroll
    for (int nj = 0; nj < 4; ++nj)
      bh[nj] = __builtin_bit_cast(
          bf16x8, *(const u16x8*)&BS[wc * 64 + nj * 16 + tn][8 * g]);
#pragma unroll
    for (int mi = 0; mi < 4; ++mi)
#pragma unroll
      for (int nj = 0; nj < 4; ++nj)
        acc[mi][nj] = MFMA16(ah[mi], bh[nj], acc[mi][nj]);
  }

#pragma unroll
  for (int mi = 0; mi < 4; ++mi) {
    const int rb = m0 + wr * 64 + mi * 16 + 4 * g;
#pragma unroll
    for (int nj = 0; nj < 4; ++nj) {
      const int col = n0 + wc * 64 + nj * 16 + tn;
      const float bb = bias[col];
#pragma unroll
      for (int r = 0; r < 4; ++r)
        outp[(size_t)(rb + r) * EDIM + col] =
            bfbits((acc[mi][nj][r] + bb) * scale);
    }
  }
}

// ---------------------------------------------------------------------------
// 3-term split MFMA GEMM (for proj): fp32-accurate, fp32 out + bias.
// ---------------------------------------------------------------------------
__global__ __launch_bounds__(256) void proj_kernel(
    const ushort_t* __restrict__ Ah, const ushort_t* __restrict__ Al,
    const ushort_t* __restrict__ Bh, const ushort_t* __restrict__ Bl,
    const float* __restrict__ bias, float* __restrict__ outf) {
  __shared__ __align__(16) ushort_t AhS[128][32];
  __shared__ __align__(16) ushort_t AlS[128][32];
  __shared__ __align__(16) ushort_t BhS[128][32];
  __shared__ __align__(16) ushort_t BlS[128][32];

  const int t = threadIdx.x;
  const int lane = t & 63;
  const int w = t >> 6;
  const int tn = t & 15;
  const int g = (t >> 4) & 3;
  const int wr = w >> 1, wc = w & 1;
  const int m0 = blockIdx.x * 128;
  const int n0 = blockIdx.y * 128;

  f32x4 acc[4][4];
#pragma unroll
  for (int mi = 0; mi < 4; ++mi)
#pragma unroll
    for (int nj = 0; nj < 4; ++nj) acc[mi][nj] = (f32x4){0.f, 0.f, 0.f, 0.f};

  const int crow = lane >> 2;
  const int ccol = (lane & 3) * 8;

  for (int k0 = 0; k0 < EDIM; k0 += 32) {
    __syncthreads();
#pragma unroll
    for (int i = 0; i < 2; ++i) {
      const int ch = w + 4 * i;
      const int row = ch * 16 + crow;
      const size_t ga = (size_t)(m0 + row) * EDIM + k0 + ccol;
      const size_t gb = (size_t)(n0 + row) * EDIM + k0 + ccol;
      GLOAD_LDS16(Ah + ga, &AhS[ch * 16][0]);
      GLOAD_LDS16(Al + ga, &AlS[ch * 16][0]);
      GLOAD_LDS16(Bh + gb, &BhS[ch * 16][0]);
      GLOAD_LDS16(Bl + gb, &BlS[ch * 16][0]);
    }
    __syncthreads();

    bf16x8 ah[4], al[4], bh[4], bl[4];
#pragma unroll
    for (int mi = 0; mi < 4; ++mi) {
      ah[mi] = __builtin_bit_cast(
          bf16x8, *(const u16x8*)&AhS[wr * 64 + mi * 16 + tn][8 * g]);
      al[mi] = __builtin_bit_cast(
          bf16x8, *(const u16x8*)&AlS[wr * 64 + mi * 16 + tn][8 * g]);
    }
#pragma unroll
    for (int nj = 0; nj < 4; ++nj) {
      bh[nj] = __builtin_bit_cast(
          bf16x8, *(const u16x8*)&BhS[wc * 64 + nj * 16 + tn][8 * g]);
      bl[nj] = __builtin_bit_cast(
          bf16x8, *(const u16x8*)&BlS[wc * 64 + nj * 16 + tn][8 * g]);
    }
#pragma unroll
    for (int mi = 0; mi < 4; ++mi)
#pragma unroll
      for (int nj = 0; nj < 4; ++nj)
        acc[mi][nj] = MFMA16(ah[mi], bh[nj], acc[mi][nj]);
#pragma unroll
    for (int mi = 0; mi < 4; ++mi)
#pragma unroll
      for (int nj = 0; nj < 4; ++nj)
        acc[mi][nj] = MFMA16(al[mi], bh[nj], acc[mi][nj]);
#pragma unroll
    for (int mi = 0; mi < 4; ++mi)
#pragma unroll
      for (int nj = 0; nj < 4; ++nj)
        acc[mi][nj] = MFMA16(ah[mi], bl[nj], acc[mi][nj]);
  }

#pragma unroll
  for (int mi = 0; mi < 4; ++mi) {
    const int rb = m0 + wr * 64 + mi * 16 + 4 * g;
#pragma unroll
    for (int nj = 0; nj < 4; ++nj) {
      const int col = n0 + wc * 64 + nj * 16 + tn;
      const float bb = bias[col];
#pragma unroll
      for (int r = 0; r < 4; ++r)
        outf[(size_t)(rb + r) * EDIM + col] = acc[mi][nj][r] + bb;
    }
  }
}

// ---------------------------------------------------------------------------
// MFMA flash attention, 256 thr / 4 waves x 16 q (12 waves/CU).
//  - K and V^T staged via global_load_lds (width 16) into linear [64][64]
//    double-buffered LDS tiles: ZERO wave ds_write instructions.
//  - XOR swizzle (byte ^= (row&7)<<4): inverse-swizzled GLOBAL source +
//    linear LDS dest + swizzled LDS read -> 2-way (free) fragment reads.
//  - One barrier per tile (m97 schedule): barrier drains prev DMAs, then
//    next tile's DMAs are issued and fly under this tile's compute.
//  - Swapped QK^T (s = mfma(K,Q)): P written as 4 packed b64, not 16 b16.
//  - No-max exp2 softmax, rowsum via ones-MFMA. C written hi/lo split.
// ---------------------------------------------------------------------------
__global__ __launch_bounds__(256) void attn_kernel(
    const ushort_t* __restrict__ QB, const ushort_t* __restrict__ KBg,
    const ushort_t* __restrict__ VTg, ushort_t* __restrict__ Ch_g,
    ushort_t* __restrict__ Cl_g) {
  __shared__ __align__(16) ushort_t KS[2][64][64];  // [buf][key][d]
  __shared__ __align__(16) ushort_t VS[2][64][64];  // [buf][d][key]
  __shared__ __align__(16) ushort_t Ps[4][16][72];  // per-wave P[q][key]

  const int t = threadIdx.x;
  const int lane = t & 63;
  const int tn = t & 15;
  const int g = (t >> 4) & 3;
  const int kg = g * 8;
  const int wid = t >> 6;
  const int h = blockIdx.y;
  const int q0 = blockIdx.x * 64;
  const int hoff = h * HDIM;

  // Q fragments (pre-scaled bf16) — B-operand of the swapped QK^T
  bf16x8 qb[2];
  {
    const size_t qoff = (size_t)(q0 + 16 * wid + tn) * EDIM + hoff;
    qb[0] = __builtin_bit_cast(bf16x8, *(const u16x8*)(QB + qoff + kg));
    qb[1] = __builtin_bit_cast(bf16x8, *(const u16x8*)(QB + qoff + 32 + kg));
  }

  // gload_lds staging roles: wave wid covers rows 16*wid..16*wid+15 of both
  // tiles; 2 calls of 8 rows. Global source pre-XOR-swizzled (rule #21).
  const int srow = lane >> 3;                        // 0..7 within call
  const int sxor = ((lane & 7) ^ srow) << 4;         // byte offset in row
  const int rswz = (tn & 7) << 4;                    // read-side XOR

  const bf16x8 ones = ones8();
  f32x4 o[4], lsum;
#pragma unroll
  for (int j = 0; j < 4; ++j) o[j] = (f32x4){0.f, 0.f, 0.f, 0.f};
  lsum = (f32x4){0.f, 0.f, 0.f, 0.f};

  // prologue: stage tile 0 into buf 0
#pragma unroll
  for (int c = 0; c < 2; ++c) {
    const int row = 16 * wid + 8 * c + srow;
    GLOAD_LDS16((const char*)(KBg + (size_t)row * EDIM + hoff) + sxor,
                &KS[0][16 * wid + 8 * c][0]);
    GLOAD_LDS16((const char*)(VTg + (size_t)(hoff + row) * SEQ) + sxor,
                &VS[0][16 * wid + 8 * c][0]);
  }

  for (int it = 0; it < SEQ / 64; ++it) {
    const int buf = it & 1;
    __syncthreads();  // drains own DMAs (vmcnt) + all waves done with buf^1

    if (it + 1 < SEQ / 64) {  // stage next tile into buf^1
      const int k0n = (it + 1) * 64;
#pragma unroll
      for (int c = 0; c < 2; ++c) {
        const int row = 16 * wid + 8 * c + srow;
        GLOAD_LDS16(
            (const char*)(KBg + (size_t)(k0n + row) * EDIM + hoff) + sxor,
            &KS[buf ^ 1][16 * wid + 8 * c][0]);
        GLOAD_LDS16(
            (const char*)(VTg + (size_t)(hoff + row) * SEQ + k0n) + sxor,
            &VS[buf ^ 1][16 * wid + 8 * c][0]);
      }
    }

    // S^T = K Q : lane holds S[key=16kb+4g+r][q=tn] (swizzled K reads)
    f32x4 s[4];
#pragma unroll
    for (int kb = 0; kb < 4; ++kb) {
      const char* krow = (const char*)&KS[buf][16 * kb + tn][0];
      const bf16x8 ka = __builtin_bit_cast(
          bf16x8, *(const u16x8*)(krow + ((16 * g) ^ rswz)));
      const bf16x8 kc = __builtin_bit_cast(
          bf16x8, *(const u16x8*)(krow + ((64 + 16 * g) ^ rswz)));
      s[kb] = (f32x4){0.f, 0.f, 0.f, 0.f};
      s[kb] = MFMA16(ka, qb[0], s[kb]);
      s[kb] = MFMA16(kc, qb[1], s[kb]);
    }

    // p = 2^s ; packed P write: row q=tn, keys 16kb+4g..+3 (one b64 per kb)
#pragma unroll
    for (int kb = 0; kb < 4; ++kb) {
      uint2 pk;
      pk.x = (uint_t)bfbits(exp2f(s[kb][0])) |
             ((uint_t)bfbits(exp2f(s[kb][1])) << 16);
      pk.y = (uint_t)bfbits(exp2f(s[kb][2])) |
             ((uint_t)bfbits(exp2f(s[kb][3])) << 16);
      *(uint2*)&Ps[wid][tn][16 * kb + 4 * g] = pk;
    }

    // pa: A-operand P[q=tn][keys 32st+kg..+7] (wave-local, lgkmcnt-ordered)
    const bf16x8 pa0 =
        __builtin_bit_cast(bf16x8, *(const u16x8*)&Ps[wid][tn][kg]);
    const bf16x8 pa1 =
        __builtin_bit_cast(bf16x8, *(const u16x8*)&Ps[wid][tn][32 + kg]);

    // O += P V ; lsum += P @ ones (swizzled V reads)
#pragma unroll
    for (int j = 0; j < 4; ++j) {
      const char* vrow = (const char*)&VS[buf][16 * j + tn][0];
      const bf16x8 v0 = __builtin_bit_cast(
          bf16x8, *(const u16x8*)(vrow + ((16 * g) ^ rswz)));
      const bf16x8 v1 = __builtin_bit_cast(
          bf16x8, *(const u16x8*)(vrow + ((64 + 16 * g) ^ rswz)));
      o[j] = MFMA16(pa0, v0, o[j]);
      o[j] = MFMA16(pa1, v1, o[j]);
    }
    lsum = MFMA16(pa0, ones, lsum);
    lsum = MFMA16(pa1, ones, lsum);
  }

  // epilogue: normalize, split hi/lo, store C
#pragma unroll
  for (int r = 0; r < 4; ++r) {
    const float inv = 1.f / lsum[r];
#pragma unroll
    for (int j = 0; j < 4; ++j) {
      const float val = o[j][r] * inv;
      unsigned short hh, ll;
      split1(val, &hh, &ll);
      const size_t idx =
          (size_t)(q0 + 16 * wid + 4 * g + r) * EDIM + hoff + 16 * j + tn;
      Ch_g[idx] = hh;
      Cl_g[idx] = ll;
    }
  }
}

extern "C" void kernel_launch(void* const* d_in, const int* in_sizes, int n_in,
                              void* d_out, int out_size, void* d_ws,
                              size_t ws_size, hipStream_t stream) {
  const float* x  = (const float*)d_in[0];
  const float* Wq = (const float*)d_in[1];
  const float* bq = (const float*)d_in[2];
  const float* Wk = (const float*)d_in[3];
  const float* bk = (const float*)d_in[4];
  const float* Wv = (const float*)d_in[5];
  const float* bv = (const float*)d_in[6];
  const float* Wo = (const float*)d_in[7];
  const float* bo = (const float*)d_in[8];
  float* out = (float*)d_out;

  // ws layout, u16 elements (~50 MB, within proven budget)
  ushort_t* WB  = (ushort_t*)d_ws;              // 3*WMAT (Wq,Wk,Wv bf16)
  ushort_t* WOH = WB + (size_t)3 * WMAT;        // WMAT
  ushort_t* WOL = WOH + (size_t)WMAT;           // WMAT
  ushort_t* XB  = WOL + (size_t)WMAT;           // SE
  ushort_t* QB  = XB + (size_t)SE;              // SE
  ushort_t* KB  = QB + (size_t)SE;              // SE
  ushort_t* VB  = KB + (size_t)SE;              // SE
  ushort_t* VT  = VB + (size_t)SE;              // SE (V^T [768][4096])
  ushort_t* CH  = VT + (size_t)SE;              // SE
  ushort_t* CL  = CH + (size_t)SE;              // SE

  dim3 gw(WMAT / 2048, 4);
  wprep_kernel<<<gw, 256, 0, stream>>>(Wq, Wk, Wv, Wo, WB, WOH, WOL);
  xprep_kernel<<<SE / 2048, 256, 0, stream>>>(x, XB);

  dim3 gq(SEQ / 128, EDIM / 128, 3);
  qkv_kernel<<<gq, 256, 0, stream>>>(XB, WB, bq, bk, bv, QB, KB, VB);

  dim3 gt(SEQ / 64, NHEAD);
  vtrans_kernel<<<gt, 256, 0, stream>>>(VB, VT);

  dim3 ga(SEQ / 64, NHEAD);
  attn_kernel<<<ga, 256, 0, stream>>>(QB, KB, VT, CH, CL);

  dim3 go(SEQ / 128, EDIM / 128);
  proj_kernel<<<go, 256, 0, stream>>>(CH, CL, WOH, WOL, bo, out);
}

// Round 9
// 167.449 us; speedup vs baseline: 1.7516x; 1.1115x over previous
//
#include <hip/hip_runtime.h>
#include <hip/hip_bf16.h>
#include <math.h>

#define SEQ 4096
#define EDIM 768
#define NHEAD 12
#define HDIM 64
#define SE (SEQ * EDIM)
#define WMAT (EDIM * EDIM)
#define QSCALE 0.180336880111f  // 0.125 * log2(e)

typedef __attribute__((ext_vector_type(8))) __bf16 bf16x8;
typedef __attribute__((ext_vector_type(4))) float f32x4;
typedef __attribute__((ext_vector_type(8))) unsigned short u16x8;
typedef unsigned short ushort_t;
typedef unsigned int uint_t;

#define MFMA16(a, b, c) __builtin_amdgcn_mfma_f32_16x16x32_bf16(a, b, c, 0, 0, 0)
#define GLOAD_LDS16(g, l)                                          \
  __builtin_amdgcn_global_load_lds(                                \
      (const __attribute__((address_space(1))) void*)(g),          \
      (__attribute__((address_space(3))) void*)(l), 16, 0, 0)

__device__ __forceinline__ unsigned short bfbits(float x) {
  return __builtin_bit_cast(unsigned short, (__bf16)x);
}
__device__ __forceinline__ void split1(float x, unsigned short* h,
                                       unsigned short* l) {
  __bf16 hb = (__bf16)x;
  *h = __builtin_bit_cast(unsigned short, hb);
  *l = __builtin_bit_cast(unsigned short, (__bf16)(x - (float)hb));
}
__device__ __forceinline__ bf16x8 ones8() {
  u16x8 u;
#pragma unroll
  for (int e = 0; e < 8; ++e) u[e] = 0x3F80;  // bf16 1.0
  return __builtin_bit_cast(bf16x8, u);
}
// bare hardware exp2: v_exp_f32 computes 2^x (1 ULP) — avoids any libm path
__device__ __forceinline__ float exp2_hw(float x) {
  float r;
  asm("v_exp_f32 %0, %1" : "=v"(r) : "v"(x));
  return r;
}

// ---------------------------------------------------------------------------
// Prep: round Wq/Wk/Wv to bf16; split Wo hi/lo; round x to bf16.
// ---------------------------------------------------------------------------
__global__ __launch_bounds__(256) void wprep_kernel(
    const float* __restrict__ W0, const float* __restrict__ W1,
    const float* __restrict__ W2, const float* __restrict__ W3,
    ushort_t* __restrict__ WB, ushort_t* __restrict__ WOH,
    ushort_t* __restrict__ WOL) {
  const int m = blockIdx.y;
  const float* src = (m == 0) ? W0 : (m == 1) ? W1 : (m == 2) ? W2 : W3;
  const size_t i = ((size_t)blockIdx.x * 256 + threadIdx.x) * 8;
  float4 a = *(const float4*)(src + i);
  float4 b = *(const float4*)(src + i + 4);
  float fv[8] = {a.x, a.y, a.z, a.w, b.x, b.y, b.z, b.w};
  if (m < 3) {
    u16x8 hh;
#pragma unroll
    for (int e = 0; e < 8; ++e) hh[e] = bfbits(fv[e]);
    *(u16x8*)(WB + (size_t)m * WMAT + i) = hh;
  } else {
    u16x8 hh, ll;
#pragma unroll
    for (int e = 0; e < 8; ++e) {
      unsigned short x, y;
      split1(fv[e], &x, &y);
      hh[e] = x;
      ll[e] = y;
    }
    *(u16x8*)(WOH + i) = hh;
    *(u16x8*)(WOL + i) = ll;
  }
}

__global__ __launch_bounds__(256) void xprep_kernel(
    const float* __restrict__ x, ushort_t* __restrict__ xb) {
  const size_t i = ((size_t)blockIdx.x * 256 + threadIdx.x) * 8;
  float4 a = *(const float4*)(x + i);
  float4 b = *(const float4*)(x + i + 4);
  float fv[8] = {a.x, a.y, a.z, a.w, b.x, b.y, b.z, b.w};
  u16x8 hh;
#pragma unroll
  for (int e = 0; e < 8; ++e) hh[e] = bfbits(fv[e]);
  *(u16x8*)(xb + i) = hh;
}

// ---------------------------------------------------------------------------
// V transpose: VB [4096][768] -> VT [768][4096], per-head 64x64 tiles.
// ---------------------------------------------------------------------------
__global__ __launch_bounds__(256) void vtrans_kernel(
    const ushort_t* __restrict__ VB, ushort_t* __restrict__ VT) {
  __shared__ ushort_t T[64][65];
  const int t = threadIdx.x;
  const int s0 = blockIdx.x * 64;
  const int hoff = blockIdx.y * 64;
  const int r = t >> 2, c = (t & 3) * 16;
  u16x8 a = *(const u16x8*)(VB + (size_t)(s0 + r) * EDIM + hoff + c);
  u16x8 b = *(const u16x8*)(VB + (size_t)(s0 + r) * EDIM + hoff + c + 8);
#pragma unroll
  for (int e = 0; e < 8; ++e) {
    T[r][c + e] = a[e];
    T[r][c + 8 + e] = b[e];
  }
  __syncthreads();
  u16x8 w0, w1;
#pragma unroll
  for (int e = 0; e < 8; ++e) {
    w0[e] = T[c + e][r];
    w1[e] = T[c + 8 + e][r];
  }
  *(u16x8*)(VT + (size_t)(hoff + r) * SEQ + s0 + c) = w0;
  *(u16x8*)(VT + (size_t)(hoff + r) * SEQ + s0 + c + 8) = w1;
}

// ---------------------------------------------------------------------------
// Single-bf16 MFMA GEMM (for QKV): out_bf16 = bf16((A@B^T + bias) * scale).
// ---------------------------------------------------------------------------
__global__ __launch_bounds__(256) void qkv_kernel(
    const ushort_t* __restrict__ XB, const ushort_t* __restrict__ WB,
    const float* __restrict__ bq, const float* __restrict__ bk,
    const float* __restrict__ bv, ushort_t* __restrict__ QB,
    ushort_t* __restrict__ KB, ushort_t* __restrict__ VB) {
  __shared__ __align__(16) ushort_t AS[128][32];
  __shared__ __align__(16) ushort_t BS[128][32];

  const int z = blockIdx.z;
  const ushort_t* Bmat = WB + (size_t)z * WMAT;
  const float* bias = (z == 0) ? bq : (z == 1) ? bk : bv;
  ushort_t* outp = (z == 0) ? QB : (z == 1) ? KB : VB;
  const float scale = (z == 0) ? QSCALE : 1.0f;

  const int t = threadIdx.x;
  const int lane = t & 63;
  const int w = t >> 6;
  const int tn = t & 15;
  const int g = (t >> 4) & 3;
  const int wr = w >> 1, wc = w & 1;
  const int m0 = blockIdx.x * 128;
  const int n0 = blockIdx.y * 128;

  f32x4 acc[4][4];
#pragma unroll
  for (int mi = 0; mi < 4; ++mi)
#pragma unroll
    for (int nj = 0; nj < 4; ++nj) acc[mi][nj] = (f32x4){0.f, 0.f, 0.f, 0.f};

  const int crow = lane >> 2;
  const int ccol = (lane & 3) * 8;

  for (int k0 = 0; k0 < EDIM; k0 += 32) {
    __syncthreads();
#pragma unroll
    for (int i = 0; i < 2; ++i) {
      const int ch = w + 4 * i;
      const int row = ch * 16 + crow;
      GLOAD_LDS16(XB + (size_t)(m0 + row) * EDIM + k0 + ccol, &AS[ch * 16][0]);
      GLOAD_LDS16(Bmat + (size_t)(n0 + row) * EDIM + k0 + ccol, &BS[ch * 16][0]);
    }
    __syncthreads();

    bf16x8 ah[4], bh[4];
#pragma unroll
    for (int mi = 0; mi < 4; ++mi)
      ah[mi] = __builtin_bit_cast(
          bf16x8, *(const u16x8*)&AS[wr * 64 + mi * 16 + tn][8 * g]);
#pragma unroll
    for (int nj = 0; nj < 4; ++nj)
      bh[nj] = __builtin_bit_cast(
          bf16x8, *(const u16x8*)&BS[wc * 64 + nj * 16 + tn][8 * g]);
#pragma unroll
    for (int mi = 0; mi < 4; ++mi)
#pragma unroll
      for (int nj = 0; nj < 4; ++nj)
        acc[mi][nj] = MFMA16(ah[mi], bh[nj], acc[mi][nj]);
  }

#pragma unroll
  for (int mi = 0; mi < 4; ++mi) {
    const int rb = m0 + wr * 64 + mi * 16 + 4 * g;
#pragma unroll
    for (int nj = 0; nj < 4; ++nj) {
      const int col = n0 + wc * 64 + nj * 16 + tn;
      const float bb = bias[col];
#pragma unroll
      for (int r = 0; r < 4; ++r)
        outp[(size_t)(rb + r) * EDIM + col] =
            bfbits((acc[mi][nj][r] + bb) * scale);
    }
  }
}

// ---------------------------------------------------------------------------
// 3-term split MFMA GEMM (for proj): fp32-accurate, fp32 out + bias.
// ---------------------------------------------------------------------------
__global__ __launch_bounds__(256) void proj_kernel(
    const ushort_t* __restrict__ Ah, const ushort_t* __restrict__ Al,
    const ushort_t* __restrict__ Bh, const ushort_t* __restrict__ Bl,
    const float* __restrict__ bias, float* __restrict__ outf) {
  __shared__ __align__(16) ushort_t AhS[128][32];
  __shared__ __align__(16) ushort_t AlS[128][32];
  __shared__ __align__(16) ushort_t BhS[128][32];
  __shared__ __align__(16) ushort_t BlS[128][32];

  const int t = threadIdx.x;
  const int lane = t & 63;
  const int w = t >> 6;
  const int tn = t & 15;
  const int g = (t >> 4) & 3;
  const int wr = w >> 1, wc = w & 1;
  const int m0 = blockIdx.x * 128;
  const int n0 = blockIdx.y * 128;

  f32x4 acc[4][4];
#pragma unroll
  for (int mi = 0; mi < 4; ++mi)
#pragma unroll
    for (int nj = 0; nj < 4; ++nj) acc[mi][nj] = (f32x4){0.f, 0.f, 0.f, 0.f};

  const int crow = lane >> 2;
  const int ccol = (lane & 3) * 8;

  for (int k0 = 0; k0 < EDIM; k0 += 32) {
    __syncthreads();
#pragma unroll
    for (int i = 0; i < 2; ++i) {
      const int ch = w + 4 * i;
      const int row = ch * 16 + crow;
      const size_t ga = (size_t)(m0 + row) * EDIM + k0 + ccol;
      const size_t gb = (size_t)(n0 + row) * EDIM + k0 + ccol;
      GLOAD_LDS16(Ah + ga, &AhS[ch * 16][0]);
      GLOAD_LDS16(Al + ga, &AlS[ch * 16][0]);
      GLOAD_LDS16(Bh + gb, &BhS[ch * 16][0]);
      GLOAD_LDS16(Bl + gb, &BlS[ch * 16][0]);
    }
    __syncthreads();

    bf16x8 ah[4], al[4], bh[4], bl[4];
#pragma unroll
    for (int mi = 0; mi < 4; ++mi) {
      ah[mi] = __builtin_bit_cast(
          bf16x8, *(const u16x8*)&AhS[wr * 64 + mi * 16 + tn][8 * g]);
      al[mi] = __builtin_bit_cast(
          bf16x8, *(const u16x8*)&AlS[wr * 64 + mi * 16 + tn][8 * g]);
    }
#pragma unroll
    for (int nj = 0; nj < 4; ++nj) {
      bh[nj] = __builtin_bit_cast(
          bf16x8, *(const u16x8*)&BhS[wc * 64 + nj * 16 + tn][8 * g]);
      bl[nj] = __builtin_bit_cast(
          bf16x8, *(const u16x8*)&BlS[wc * 64 + nj * 16 + tn][8 * g]);
    }
#pragma unroll
    for (int mi = 0; mi < 4; ++mi)
#pragma unroll
      for (int nj = 0; nj < 4; ++nj)
        acc[mi][nj] = MFMA16(ah[mi], bh[nj], acc[mi][nj]);
#pragma unroll
    for (int mi = 0; mi < 4; ++mi)
#pragma unroll
      for (int nj = 0; nj < 4; ++nj)
        acc[mi][nj] = MFMA16(al[mi], bh[nj], acc[mi][nj]);
#pragma unroll
    for (int mi = 0; mi < 4; ++mi)
#pragma unroll
      for (int nj = 0; nj < 4; ++nj)
        acc[mi][nj] = MFMA16(ah[mi], bl[nj], acc[mi][nj]);
  }

#pragma unroll
  for (int mi = 0; mi < 4; ++mi) {
    const int rb = m0 + wr * 64 + mi * 16 + 4 * g;
#pragma unroll
    for (int nj = 0; nj < 4; ++nj) {
      const int col = n0 + wc * 64 + nj * 16 + tn;
      const float bb = bias[col];
#pragma unroll
      for (int r = 0; r < 4; ++r)
        outf[(size_t)(rb + r) * EDIM + col] = acc[mi][nj][r] + bb;
    }
  }
}

// ---------------------------------------------------------------------------
// MFMA flash attention (round-8 structure; exp via bare v_exp_f32).
// ---------------------------------------------------------------------------
__global__ __launch_bounds__(256) void attn_kernel(
    const ushort_t* __restrict__ QB, const ushort_t* __restrict__ KBg,
    const ushort_t* __restrict__ VTg, ushort_t* __restrict__ Ch_g,
    ushort_t* __restrict__ Cl_g) {
  __shared__ __align__(16) ushort_t KS[2][64][64];  // [buf][key][d]
  __shared__ __align__(16) ushort_t VS[2][64][64];  // [buf][d][key]
  __shared__ __align__(16) ushort_t Ps[4][16][72];  // per-wave P[q][key]

  const int t = threadIdx.x;
  const int lane = t & 63;
  const int tn = t & 15;
  const int g = (t >> 4) & 3;
  const int kg = g * 8;
  const int wid = t >> 6;
  const int h = blockIdx.y;
  const int q0 = blockIdx.x * 64;
  const int hoff = h * HDIM;

  // Q fragments (pre-scaled bf16) — B-operand of the swapped QK^T
  bf16x8 qb[2];
  {
    const size_t qoff = (size_t)(q0 + 16 * wid + tn) * EDIM + hoff;
    qb[0] = __builtin_bit_cast(bf16x8, *(const u16x8*)(QB + qoff + kg));
    qb[1] = __builtin_bit_cast(bf16x8, *(const u16x8*)(QB + qoff + 32 + kg));
  }

  // gload_lds staging roles; global source pre-XOR-swizzled (rule #21)
  const int srow = lane >> 3;
  const int sxor = ((lane & 7) ^ srow) << 4;
  // loop-invariant swizzled read byte-offsets
  const int rswz = (tn & 7) << 4;
  const int off0 = (16 * g) ^ rswz;
  const int off1 = (64 + 16 * g) ^ rswz;

  const bf16x8 ones = ones8();
  f32x4 o[4], lsum;
#pragma unroll
  for (int j = 0; j < 4; ++j) o[j] = (f32x4){0.f, 0.f, 0.f, 0.f};
  lsum = (f32x4){0.f, 0.f, 0.f, 0.f};

  // prologue: stage tile 0 into buf 0
#pragma unroll
  for (int c = 0; c < 2; ++c) {
    const int row = 16 * wid + 8 * c + srow;
    GLOAD_LDS16((const char*)(KBg + (size_t)row * EDIM + hoff) + sxor,
                &KS[0][16 * wid + 8 * c][0]);
    GLOAD_LDS16((const char*)(VTg + (size_t)(hoff + row) * SEQ) + sxor,
                &VS[0][16 * wid + 8 * c][0]);
  }

  for (int it = 0; it < SEQ / 64; ++it) {
    const int buf = it & 1;
    __syncthreads();  // drains own DMAs + all waves done with buf^1

    if (it + 1 < SEQ / 64) {  // stage next tile into buf^1
      const int k0n = (it + 1) * 64;
#pragma unroll
      for (int c = 0; c < 2; ++c) {
        const int row = 16 * wid + 8 * c + srow;
        GLOAD_LDS16(
            (const char*)(KBg + (size_t)(k0n + row) * EDIM + hoff) + sxor,
            &KS[buf ^ 1][16 * wid + 8 * c][0]);
        GLOAD_LDS16(
            (const char*)(VTg + (size_t)(hoff + row) * SEQ + k0n) + sxor,
            &VS[buf ^ 1][16 * wid + 8 * c][0]);
      }
    }

    // S^T = K Q : lane holds S[key=16kb+4g+r][q=tn] (swizzled K reads)
    f32x4 s[4];
#pragma unroll
    for (int kb = 0; kb < 4; ++kb) {
      const char* krow = (const char*)&KS[buf][16 * kb + tn][0];
      const bf16x8 ka =
          __builtin_bit_cast(bf16x8, *(const u16x8*)(krow + off0));
      const bf16x8 kc =
          __builtin_bit_cast(bf16x8, *(const u16x8*)(krow + off1));
      s[kb] = (f32x4){0.f, 0.f, 0.f, 0.f};
      s[kb] = MFMA16(ka, qb[0], s[kb]);
      s[kb] = MFMA16(kc, qb[1], s[kb]);
    }

    // p = 2^s via v_exp_f32 ; packed P write (one b64 per kb)
#pragma unroll
    for (int kb = 0; kb < 4; ++kb) {
      uint2 pk;
      pk.x = (uint_t)bfbits(exp2_hw(s[kb][0])) |
             ((uint_t)bfbits(exp2_hw(s[kb][1])) << 16);
      pk.y = (uint_t)bfbits(exp2_hw(s[kb][2])) |
             ((uint_t)bfbits(exp2_hw(s[kb][3])) << 16);
      *(uint2*)&Ps[wid][tn][16 * kb + 4 * g] = pk;
    }

    // pa: A-operand P[q=tn][keys 32st+kg..+7] (wave-local, lgkmcnt-ordered)
    const bf16x8 pa0 =
        __builtin_bit_cast(bf16x8, *(const u16x8*)&Ps[wid][tn][kg]);
    const bf16x8 pa1 =
        __builtin_bit_cast(bf16x8, *(const u16x8*)&Ps[wid][tn][32 + kg]);

    // O += P V ; lsum += P @ ones (swizzled V reads)
#pragma unroll
    for (int j = 0; j < 4; ++j) {
      const char* vrow = (const char*)&VS[buf][16 * j + tn][0];
      const bf16x8 v0 =
          __builtin_bit_cast(bf16x8, *(const u16x8*)(vrow + off0));
      const bf16x8 v1 =
          __builtin_bit_cast(bf16x8, *(const u16x8*)(vrow + off1));
      o[j] = MFMA16(pa0, v0, o[j]);
      o[j] = MFMA16(pa1, v1, o[j]);
    }
    lsum = MFMA16(pa0, ones, lsum);
    lsum = MFMA16(pa1, ones, lsum);
  }

  // epilogue: normalize, split hi/lo, store C
#pragma unroll
  for (int r = 0; r < 4; ++r) {
    const float inv = 1.f / lsum[r];
#pragma unroll
    for (int j = 0; j < 4; ++j) {
      const float val = o[j][r] * inv;
      unsigned short hh, ll;
      split1(val, &hh, &ll);
      const size_t idx =
          (size_t)(q0 + 16 * wid + 4 * g + r) * EDIM + hoff + 16 * j + tn;
      Ch_g[idx] = hh;
      Cl_g[idx] = ll;
    }
  }
}

extern "C" void kernel_launch(void* const* d_in, const int* in_sizes, int n_in,
                              void* d_out, int out_size, void* d_ws,
                              size_t ws_size, hipStream_t stream) {
  const float* x  = (const float*)d_in[0];
  const float* Wq = (const float*)d_in[1];
  const float* bq = (const float*)d_in[2];
  const float* Wk = (const float*)d_in[3];
  const float* bk = (const float*)d_in[4];
  const float* Wv = (const float*)d_in[5];
  const float* bv = (const float*)d_in[6];
  const float* Wo = (const float*)d_in[7];
  const float* bo = (const float*)d_in[8];
  float* out = (float*)d_out;

  // ws layout, u16 elements (~50 MB)
  ushort_t* WB  = (ushort_t*)d_ws;              // 3*WMAT (Wq,Wk,Wv bf16)
  ushort_t* WOH = WB + (size_t)3 * WMAT;        // WMAT
  ushort_t* WOL = WOH + (size_t)WMAT;           // WMAT
  ushort_t* XB  = WOL + (size_t)WMAT;           // SE
  ushort_t* QB  = XB + (size_t)SE;              // SE
  ushort_t* KB  = QB + (size_t)SE;              // SE
  ushort_t* VB  = KB + (size_t)SE;              // SE
  ushort_t* VT  = VB + (size_t)SE;              // SE (V^T [768][4096])
  ushort_t* CH  = VT + (size_t)SE;              // SE
  ushort_t* CL  = CH + (size_t)SE;              // SE

  dim3 gw(WMAT / 2048, 4);
  wprep_kernel<<<gw, 256, 0, stream>>>(Wq, Wk, Wv, Wo, WB, WOH, WOL);
  xprep_kernel<<<SE / 2048, 256, 0, stream>>>(x, XB);

  dim3 gq(SEQ / 128, EDIM / 128, 3);
  qkv_kernel<<<gq, 256, 0, stream>>>(XB, WB, bq, bk, bv, QB, KB, VB);

  dim3 gt(SEQ / 64, NHEAD);
  vtrans_kernel<<<gt, 256, 0, stream>>>(VB, VT);

  dim3 ga(SEQ / 64, NHEAD);
  attn_kernel<<<ga, 256, 0, stream>>>(QB, KB, VT, CH, CL);

  dim3 go(SEQ / 128, EDIM / 128);
  proj_kernel<<<go, 256, 0, stream>>>(CH, CL, WOH, WOL, bo, out);
}